// Round 4
// baseline (806.885 us; speedup 1.0000x reference)
//
#include <hip/hip_runtime.h>
#include <math.h>

#define NNODES 262144
#define HDIM   256
#define NHEADS 8
#define HEADD  32
#define NC     100
#define NLAYER 2
#define SPLIT  24
#define NBLK   (NNODES/256)   // 1024 hist/scatter blocks

__device__ __forceinline__ float gelu_exact(float v) {
    return 0.5f * v * (1.0f + erff(v * 0.70710678118654752440f));
}

__device__ __forceinline__ float dot4(float4 a, float4 b) {
    return a.x*b.x + a.y*b.y + a.z*b.z + a.w*b.w;
}

// sum across a 256-thread block; red must be __shared__ float[4]
__device__ __forceinline__ float blk_sum256(float v, float* red, int tid) {
    #pragma unroll
    for (int m = 32; m >= 1; m >>= 1) v += __shfl_xor(v, m, 64);
    if ((tid & 63) == 0) red[tid >> 6] = v;
    __syncthreads();
    float tot = red[0] + red[1] + red[2] + red[3];
    __syncthreads();
    return tot;
}

// 8x8 transpose-reduce: lane (i,s) ends with full sum of p[s] over its 8-lane group,
// then butterfly across groups. p[0..7] are per-lane partials.
__device__ __forceinline__ float xreduce8(const float* p, int s) {
    bool s1b = (s & 1) != 0, s2b = (s & 2) != 0, s4b = (s & 4) != 0;
    float a0 = __shfl_xor(p[0], 1, 64), a1 = __shfl_xor(p[1], 1, 64);
    float q0 = s1b ? (p[1] + a1) : (p[0] + a0);
    float a2 = __shfl_xor(p[2], 1, 64), a3 = __shfl_xor(p[3], 1, 64);
    float q1 = s1b ? (p[3] + a3) : (p[2] + a2);
    float a4 = __shfl_xor(p[4], 1, 64), a5 = __shfl_xor(p[5], 1, 64);
    float q2 = s1b ? (p[5] + a5) : (p[4] + a4);
    float a6 = __shfl_xor(p[6], 1, 64), a7 = __shfl_xor(p[7], 1, 64);
    float q3 = s1b ? (p[7] + a7) : (p[6] + a6);
    float b0 = __shfl_xor(q0, 2, 64), b1 = __shfl_xor(q1, 2, 64);
    float r0 = s2b ? (q1 + b1) : (q0 + b0);
    float b2 = __shfl_xor(q2, 2, 64), b3 = __shfl_xor(q3, 2, 64);
    float r1 = s2b ? (q3 + b3) : (q2 + b2);
    float c0 = __shfl_xor(r0, 4, 64), c1 = __shfl_xor(r1, 4, 64);
    float tt = s4b ? (r1 + c1) : (r0 + c0);
    tt += __shfl_xor(tt, 8, 64);
    tt += __shfl_xor(tt, 16, 64);
    tt += __shfl_xor(tt, 32, 64);
    return tt;
}

// ---------------- fused: per-block histogram (blocks < NBLK) + qkw fold (8 blocks) ----------------
__global__ __launch_bounds__(256) void k_pre(const int* __restrict__ cidx,
        const float* __restrict__ q, const float* __restrict__ kw,
        const float* __restrict__ kb, int* __restrict__ hist,
        float* __restrict__ qk_w, float* __restrict__ qk_b) {
    __shared__ int l_hist[NC];
    int tid = threadIdx.x;
    if (blockIdx.x < NBLK) {
        for (int i = tid; i < NC; i += 256) l_hist[i] = 0;
        __syncthreads();
        int c = cidx[blockIdx.x * 256 + tid];
        atomicAdd(&l_hist[c], 1);
        __syncthreads();
        for (int i = tid; i < NC; i += 256) hist[blockIdx.x*NC + i] = l_hist[i];
    } else {
        int h = blockIdx.x - NBLK, j = tid;
        float s = 0.f;
        #pragma unroll
        for (int d = 0; d < HEADD; ++d) s += q[h*HEADD + d] * kw[(h*HEADD + d)*HDIM + j];
        qk_w[h*HDIM + j] = s;
        if (j == 0) {
            float sb = 0.f;
            #pragma unroll
            for (int d = 0; d < HEADD; ++d) sb += q[h*HEADD + d] * kb[h*HEADD + d];
            qk_b[h] = sb;
        }
    }
}

// ---------------- per-commit exclusive scan over block histograms ----------------
__global__ __launch_bounds__(256) void k_blockscan(const int* __restrict__ hist,
        int* __restrict__ bbase, int* __restrict__ counts) {
    int c = blockIdx.x, t = threadIdx.x;
    int v[4]; int loc = 0;
    #pragma unroll
    for (int i = 0; i < 4; ++i) { v[i] = hist[(t*4 + i)*NC + c]; loc += v[i]; }
    __shared__ int sc[256];
    sc[t] = loc; __syncthreads();
    for (int off = 1; off < 256; off <<= 1) {
        int x = (t >= off) ? sc[t - off] : 0;
        __syncthreads();
        sc[t] += x;
        __syncthreads();
    }
    int run = (t > 0) ? sc[t-1] : 0;
    #pragma unroll
    for (int i = 0; i < 4; ++i) { bbase[(t*4 + i)*NC + c] = run; run += v[i]; }
    if (t == 255) counts[c] = sc[255];
}

// ---------------- scatter into buckets; in-block offs scan; block 0 publishes offs ----------------
__global__ __launch_bounds__(256) void k_scatter(const int* __restrict__ cidx,
        const int* __restrict__ counts, const int* __restrict__ bbase,
        int* __restrict__ nlist, int* __restrict__ offs_g) {
    __shared__ int cl[128];
    __shared__ int sb[NC];
    __shared__ int lcur[NC];
    int t = threadIdx.x, blk = blockIdx.x;
    if (t < 128) cl[t] = (t < NC) ? counts[t] : 0;
    __syncthreads();
    for (int off = 1; off < 128; off <<= 1) {
        int x = (t >= off && t < 128) ? cl[t - off] : 0;
        __syncthreads();
        if (t < 128) cl[t] += x;
        __syncthreads();
    }
    if (t < NC) {
        int o = (t > 0) ? cl[t-1] : 0;
        sb[t] = o + bbase[blk*NC + t];
        lcur[t] = 0;
        if (blk == 0) offs_g[t] = o;
    }
    __syncthreads();
    int n = blk * 256 + t;
    int c = cidx[n];
    int p = atomicAdd(&lcur[c], 1);
    nlist[sb[c] + p] = n;
}

// ---------------- fused scores + weighted accumulation (single emb pass, high ILP) ----------------
__global__ __launch_bounds__(256) void k_accum(const float* __restrict__ emb,
        const int* __restrict__ nlist, const int* __restrict__ offs,
        const int* __restrict__ counts, const float* __restrict__ qk_w,
        const float* __restrict__ qk_b, float* __restrict__ S_part,
        float* __restrict__ den_part) {
    int c  = blockIdx.x / SPLIT;
    int sl = blockIdx.x % SPLIT;
    int cnt = counts[c];
    __shared__ float s_acc[NHEADS*HDIM];   // 8 KB, shared across waves via LDS atomics
    __shared__ float s_den[NHEADS];
    int tid = threadIdx.x, w = tid >> 6, lane = tid & 63;
    int s = lane & 7, i = lane >> 3;
    const float scale = 0.17677669529663688f;  // 32^-0.5

    for (int idx = tid; idx < NHEADS*HDIM; idx += 256) s_acc[idx] = 0.f;
    if (tid < NHEADS) s_den[tid] = 0.f;
    __syncthreads();

    float4 w4[NHEADS];
    #pragma unroll
    for (int h = 0; h < NHEADS; ++h)
        w4[h] = ((const float4*)(qk_w + h*HDIM))[lane];
    float qkb_s = qk_b[s];

    float4 acc[NHEADS];
    #pragma unroll
    for (int h = 0; h < NHEADS; ++h) acc[h] = make_float4(0.f, 0.f, 0.f, 0.f);
    float den_l = 0.f;

    int beg = offs[c];
    int per = (cnt + SPLIT - 1) / SPLIT;
    int s0 = min(cnt, sl * per), s1 = min(cnt, s0 + per);

    for (int base = s0 + w*8; base < s1; base += 32) {
        // branchless: clamp out-of-range row indices to a valid one; zero their ev later
        int gi = beg + min(base + i, s1 - 1);
        int nn = nlist[gi];
        int n2[8];
        #pragma unroll
        for (int r = 0; r < 8; ++r) n2[r] = __shfl(nn, r*8, 64);
        float4 e4[8];
        #pragma unroll
        for (int r = 0; r < 8; ++r)
            e4[r] = ((const float4*)(emb + (size_t)n2[r] * HDIM))[lane];

        float tt[8];
        #pragma unroll
        for (int r = 0; r < 8; ++r) {
            float p[8];
            #pragma unroll
            for (int h = 0; h < 8; ++h) p[h] = dot4(e4[r], w4[h]);
            tt[r] = xreduce8(p, s);   // 8 independent chains -> overlapped
        }
        #pragma unroll
        for (int r = 0; r < 8; ++r) {
            // wave-uniform validity; ev=0 kills invalid rows' contribution
            float ev = ((base + r) < s1) ? __expf((tt[r] + qkb_s) * scale) : 0.f;
            den_l += ev;
            int evi = __float_as_int(ev);
            #pragma unroll
            for (int h = 0; h < 8; ++h) {
                float ee = __int_as_float(__builtin_amdgcn_readlane(evi, h)); // VALU bcast
                acc[h].x += ee * e4[r].x; acc[h].y += ee * e4[r].y;
                acc[h].z += ee * e4[r].z; acc[h].w += ee * e4[r].w;
            }
        }
    }
    // epilogue: LDS float atomics (one-time)
    #pragma unroll
    for (int h = 0; h < NHEADS; ++h) {
        atomicAdd(&s_acc[h*HDIM + lane*4 + 0], acc[h].x);
        atomicAdd(&s_acc[h*HDIM + lane*4 + 1], acc[h].y);
        atomicAdd(&s_acc[h*HDIM + lane*4 + 2], acc[h].z);
        atomicAdd(&s_acc[h*HDIM + lane*4 + 3], acc[h].w);
    }
    if (lane < 8) atomicAdd(&s_den[lane], den_l);   // group-0 value per head
    __syncthreads();
    float* Sd = S_part + ((size_t)sl*NC + c) * (NHEADS*HDIM);
    #pragma unroll
    for (int k = 0; k < 8; ++k) {
        int idx = k*256 + tid;
        Sd[idx] = s_acc[idx];
    }
    if (tid < 8)
        den_part[(sl*NC + c)*NHEADS + tid] = s_den[tid] * 0.25f;  // 4 waves added identical copies
}

// ---------------- fused: pool -> po proj -> LN -> x ; + layer-0 qkv projection ----------------
__global__ __launch_bounds__(256) void k_poolqkv(const float* __restrict__ S_part,
        const float* __restrict__ den_part, const int* __restrict__ counts,
        const float* __restrict__ vw, const float* __restrict__ vb,
        const float* __restrict__ pow_, const float* __restrict__ pob,
        const float* __restrict__ png, const float* __restrict__ pnb,
        const float* __restrict__ tinw, const float* __restrict__ tinb,
        float* __restrict__ x, float* __restrict__ qkv) {
    int c = blockIdx.x, t = threadIdx.x;
    __shared__ float S_l[NHEADS*HDIM];
    __shared__ float pooled[HDIM];
    __shared__ float x_l[HDIM];
    __shared__ float red[4];
    {
        float4 a0 = make_float4(0.f,0.f,0.f,0.f), a1 = a0;
        #pragma unroll
        for (int sl = 0; sl < SPLIT; ++sl) {
            const float4* sp = (const float4*)(S_part + ((size_t)sl*NC + c) * (NHEADS*HDIM));
            float4 v0 = sp[t], v1 = sp[t + 256];
            a0.x += v0.x; a0.y += v0.y; a0.z += v0.z; a0.w += v0.w;
            a1.x += v1.x; a1.y += v1.y; a1.z += v1.z; a1.w += v1.w;
        }
        ((float4*)S_l)[t] = a0;
        ((float4*)S_l)[t + 256] = a1;
    }
    int h = t >> 5;
    float dh = 0.f;
    #pragma unroll
    for (int sl = 0; sl < SPLIT; ++sl) dh += den_part[(sl*NC + c)*NHEADS + h];
    __syncthreads();
    float dx = dh > 0.f ? dh : 1.f;
    float s = vb[t] * dh;
    const float4* wr = (const float4*)(vw + (size_t)t * HDIM);
    const float4* sr = (const float4*)(S_l + h * HDIM);
    #pragma unroll 8
    for (int j = 0; j < HDIM/4; ++j) s += dot4(wr[j], sr[j]);
    pooled[t] = s / dx;
    __syncthreads();
    float o = pob[t];
    const float4* pr = (const float4*)(pow_ + (size_t)t * HDIM);
    const float4* pv = (const float4*)pooled;
    #pragma unroll 8
    for (int j = 0; j < HDIM/4; ++j) o += dot4(pr[j], pv[j]);
    float mu  = blk_sum256(o, red, t) * (1.f/256.f);
    float d   = o - mu;
    float var = blk_sum256(d*d, red, t) * (1.f/256.f);
    float y = d * rsqrtf(var + 1e-5f) * png[t] + pnb[t];
    float xv = (counts[c] > 0) ? y : 0.f;
    x[c*HDIM + t] = xv;
    x_l[t] = xv;
    __syncthreads();
    // layer-0 qkv projection: 3 outputs per thread
    #pragma unroll
    for (int k3 = 0; k3 < 3; ++k3) {
        int p = k3*256 + t;
        float acc = tinb[p];
        const float4* wr2 = (const float4*)(tinw + (size_t)p * HDIM);
        const float4* xv4 = (const float4*)x_l;
        #pragma unroll 8
        for (int j = 0; j < HDIM/4; ++j) acc += dot4(wr2[j], xv4[j]);
        qkv[c*3*HDIM + p] = acc;
    }
}

// ---------------- generic small matmul: out[r][p] = in[r,:] . W[p,:] + b ----------------
__global__ __launch_bounds__(256) void k_mm(const float* __restrict__ in,
        const float* __restrict__ W, const float* __restrict__ bias,
        float* __restrict__ out, int K, int P) {
    int r = blockIdx.x;
    int p = blockIdx.y * 256 + threadIdx.x;
    __shared__ float xr[256];
    for (int idx = threadIdx.x; idx < K; idx += 256) xr[idx] = in[(size_t)r*K + idx];
    __syncthreads();
    float s = bias[p];
    const float4* wr = (const float4*)(W + (size_t)p * K);
    const float4* xv = (const float4*)xr;
    for (int j = 0; j < (K >> 2); ++j) s += dot4(wr[j], xv[j]);
    out[(size_t)r*P + p] = s;
}

// ---------------- fused attention + out-proj + residual + LN (one block per query) ----------------
#define KPAD 260
__global__ __launch_bounds__(256) void k_attn_out(const float* __restrict__ qkv,
        const float* __restrict__ toutw, const float* __restrict__ toutb,
        const float* __restrict__ g, const float* __restrict__ be,
        float* __restrict__ x) {
    int r = blockIdx.x, t = threadIdx.x;
    __shared__ float k_l[NC * KPAD];    // 101.6 KB (padded for banks + f4 alignment)
    __shared__ float q_l[HDIM];
    __shared__ float o_l[HDIM];
    __shared__ float a_l[NHEADS * NC];
    __shared__ float red[4];
    for (int idx = t; idx < NC*HDIM; idx += 256) {
        int m = idx >> 8, j = idx & 255;
        k_l[m*KPAD + j] = qkv[m*768 + 256 + j];
    }
    q_l[t] = qkv[r*768 + t];
    __syncthreads();
    const float scale = 0.17677669529663688f;
    for (int idx = t; idx < NHEADS*128; idx += 256) {
        int h = idx >> 7, m = idx & 127;
        if (m < NC) {
            const float4* q4 = (const float4*)(q_l + h*HEADD);
            const float4* k4 = (const float4*)(k_l + m*KPAD + h*HEADD);
            float s = 0.f;
            #pragma unroll
            for (int j = 0; j < HEADD/4; ++j) s += dot4(q4[j], k4[j]);
            a_l[h*NC + m] = s * scale;
        }
    }
    __syncthreads();
    if (t < NHEADS) {
        float mx = -1e30f;
        for (int m = 0; m < NC; ++m) mx = fmaxf(mx, a_l[t*NC + m]);
        float sum = 0.f;
        for (int m = 0; m < NC; ++m) { float e = __expf(a_l[t*NC + m] - mx); a_l[t*NC + m] = e; sum += e; }
        float inv = 1.f / sum;
        for (int m = 0; m < NC; ++m) a_l[t*NC + m] *= inv;
    }
    __syncthreads();
    {
        int h = t >> 5;
        float o = 0.f;
        #pragma unroll 4
        for (int m = 0; m < NC; ++m) o += a_l[h*NC + m] * qkv[m*768 + 512 + t];
        o_l[t] = o;
    }
    __syncthreads();
    float s = toutb[t];
    const float4* wr = (const float4*)(toutw + (size_t)t * HDIM);
    const float4* ov = (const float4*)o_l;
    #pragma unroll 8
    for (int j = 0; j < HDIM/4; ++j) s += dot4(wr[j], ov[j]);
    float v = x[r*HDIM + t] + s;
    float mu  = blk_sum256(v, red, t) * (1.f/256.f);
    float d   = v - mu;
    float var = blk_sum256(d*d, red, t) * (1.f/256.f);
    x[r*HDIM + t] = d * rsqrtf(var + 1e-5f) * g[t] + be[t];
}

// ---------------- fused FF1 + gelu + FF2 + residual + LN (1024 threads per commit) ----------------
__global__ __launch_bounds__(1024) void k_ffn(const float* __restrict__ ff1w,
        const float* __restrict__ ff1b, const float* __restrict__ ff2w,
        const float* __restrict__ ff2b, const float* __restrict__ g,
        const float* __restrict__ be, float* __restrict__ x) {
    int r = blockIdx.x, t = threadIdx.x;
    __shared__ float x_l[HDIM];
    __shared__ float ff_l[4*HDIM];
    __shared__ float part[4*HDIM];
    __shared__ float red[16];
    if (t < HDIM) x_l[t] = x[r*HDIM + t];
    __syncthreads();
    {
        float s = ff1b[t];
        const float4* wr = (const float4*)(ff1w + (size_t)t * HDIM);
        const float4* xv = (const float4*)x_l;
        #pragma unroll 8
        for (int j = 0; j < HDIM/4; ++j) s += dot4(wr[j], xv[j]);
        ff_l[t] = gelu_exact(s);
    }
    __syncthreads();
    int p = t & 255, qd = t >> 8;
    {
        float s = 0.f;
        const float4* wr = (const float4*)(ff2w + (size_t)p * (4*HDIM) + qd*HDIM);
        const float4* fv = (const float4*)(ff_l + qd*HDIM);
        #pragma unroll 8
        for (int j = 0; j < HDIM/4; ++j) s += dot4(wr[j], fv[j]);
        part[qd*HDIM + p] = s;
    }
    __syncthreads();
    float v = 0.f;
    if (t < HDIM)
        v = part[t] + part[HDIM + t] + part[2*HDIM + t] + part[3*HDIM + t]
          + ff2b[t] + x_l[t];
    // LN over the 256 values held by threads 0..255 (others contribute 0)
    float sv = v;
    #pragma unroll
    for (int m = 32; m >= 1; m >>= 1) sv += __shfl_xor(sv, m, 64);
    if ((t & 63) == 0) red[t >> 6] = sv;
    __syncthreads();
    float mu = (red[0] + red[1] + red[2] + red[3]) * (1.f/256.f);
    float d = (t < HDIM) ? (v - mu) : 0.f;
    __syncthreads();
    float sv2 = d*d;
    #pragma unroll
    for (int m = 32; m >= 1; m >>= 1) sv2 += __shfl_xor(sv2, m, 64);
    if ((t & 63) == 0) red[t >> 6] = sv2;
    __syncthreads();
    float var = (red[0] + red[1] + red[2] + red[3]) * (1.f/256.f);
    if (t < HDIM) x[r*HDIM + t] = d * rsqrtf(var + 1e-5f) * g[t] + be[t];
}

// ---------------- ranking head ----------------
__global__ __launch_bounds__(128) void k_head(const float* __restrict__ x,
        const float* __restrict__ r1w, const float* __restrict__ r1b,
        const float* __restrict__ r2w, const float* __restrict__ r2b,
        float* __restrict__ out) {
    int r = blockIdx.x, t = threadIdx.x;
    __shared__ float xr[HDIM];
    __shared__ float red[2];
    xr[t] = x[r*HDIM + t];
    xr[t + 128] = x[r*HDIM + t + 128];
    __syncthreads();
    float s = r1b[t];
    const float4* wr = (const float4*)(r1w + (size_t)t * HDIM);
    const float4* xv = (const float4*)xr;
    #pragma unroll 8
    for (int j = 0; j < HDIM/4; ++j) s += dot4(wr[j], xv[j]);
    s = gelu_exact(s);
    float contrib = s * r2w[t];
    #pragma unroll
    for (int m = 32; m >= 1; m >>= 1) contrib += __shfl_xor(contrib, m, 64);
    if ((t & 63) == 0) red[t >> 6] = contrib;
    __syncthreads();
    if (t == 0) out[r] = red[0] + red[1] + r2b[0];
}

extern "C" void kernel_launch(void* const* d_in, const int* in_sizes, int n_in,
                              void* d_out, int out_size, void* d_ws, size_t ws_size,
                              hipStream_t stream) {
    const float* emb   = (const float*)d_in[0];
    const int*   cidx  = (const int*)d_in[1];
    const float* q     = (const float*)d_in[3];
    const float* kw    = (const float*)d_in[4];
    const float* kb    = (const float*)d_in[5];
    const float* vw    = (const float*)d_in[6];
    const float* vb    = (const float*)d_in[7];
    const float* pow_  = (const float*)d_in[8];
    const float* pob   = (const float*)d_in[9];
    const float* png   = (const float*)d_in[10];
    const float* pnb   = (const float*)d_in[11];
    const float* tinw  = (const float*)d_in[12];
    const float* tinb  = (const float*)d_in[13];
    const float* toutw = (const float*)d_in[14];
    const float* toutb = (const float*)d_in[15];
    const float* ln1g  = (const float*)d_in[16];
    const float* ln1b  = (const float*)d_in[17];
    const float* ff1w  = (const float*)d_in[18];
    const float* ff1b  = (const float*)d_in[19];
    const float* ff2w  = (const float*)d_in[20];
    const float* ff2b  = (const float*)d_in[21];
    const float* ln2g  = (const float*)d_in[22];
    const float* ln2b  = (const float*)d_in[23];
    const float* r1w   = (const float*)d_in[24];
    const float* r1b   = (const float*)d_in[25];
    const float* r2w   = (const float*)d_in[26];
    const float* r2b   = (const float*)d_in[27];
    float* out = (float*)d_out;

    char* ws = (char*)d_ws;
    size_t off = 0;
    auto alloc = [&](size_t bytes) -> char* {
        off = (off + 255) & ~(size_t)255;
        char* p = ws + off;
        off += bytes;
        return p;
    };
    int*   hist   = (int*)alloc((size_t)NBLK * NC * 4);
    int*   bbase  = (int*)alloc((size_t)NBLK * NC * 4);
    int*   counts = (int*)alloc(NC * 4);
    int*   offs   = (int*)alloc(NC * 4);
    float* den_p  = (float*)alloc((size_t)SPLIT * NC * NHEADS * 4);
    float* S_part = (float*)alloc((size_t)SPLIT * NC * NHEADS * HDIM * 4);   // 19.7 MB
    float* qk_w   = (float*)alloc(NHEADS * HDIM * 4);
    float* qk_b   = (float*)alloc(NHEADS * 4);
    int*   nlist  = (int*)alloc((size_t)NNODES * 4);
    float* x      = (float*)alloc(NC * HDIM * 4);
    float* qkv    = (float*)alloc(NC * 3 * HDIM * 4);
    (void)ws_size; (void)in_sizes; (void)n_in; (void)out_size;

    k_pre<<<NBLK + NHEADS, 256, 0, stream>>>(cidx, q, kw, kb, hist, qk_w, qk_b);
    k_blockscan<<<NC, 256, 0, stream>>>(hist, bbase, counts);
    k_scatter<<<NBLK, 256, 0, stream>>>(cidx, counts, bbase, nlist, offs);
    k_accum<<<NC*SPLIT, 256, 0, stream>>>(emb, nlist, offs, counts, qk_w, qk_b, S_part, den_p);
    k_poolqkv<<<NC, 256, 0, stream>>>(S_part, den_p, counts, vw, vb, pow_, pob, png, pnb,
                                      tinw, tinb, x, qkv);
    // layer 0
    k_attn_out<<<NC, 256, 0, stream>>>(qkv, toutw, toutb, ln1g, ln1b, x);
    k_ffn<<<NC, 1024, 0, stream>>>(ff1w, ff1b, ff2w, ff2b, ln2g, ln2b, x);
    // layer 1
    k_mm<<<dim3(NC, 3), 256, 0, stream>>>(x, tinw + (size_t)3*HDIM*HDIM,
                                          tinb + (size_t)3*HDIM, qkv, HDIM, 3*HDIM);
    k_attn_out<<<NC, 256, 0, stream>>>(qkv, toutw + (size_t)HDIM*HDIM, toutb + HDIM,
                                       ln1g + HDIM, ln1b + HDIM, x);
    k_ffn<<<NC, 1024, 0, stream>>>(ff1w + (size_t)4*HDIM*HDIM, ff1b + 4*HDIM,
                                   ff2w + (size_t)HDIM*4*HDIM, ff2b + HDIM,
                                   ln2g + HDIM, ln2b + HDIM, x);
    k_head<<<NC, 128, 0, stream>>>(x, r1w, r1b, r2w, r2b, out);
}